// Round 2
// baseline (92.907 us; speedup 1.0000x reference)
//
#include <hip/hip_runtime.h>

// PS-ROI Align: img (1,20,20,1568) f32, rois (1,8192,4) f32 -> out (1,8192,7,7,32) f32
// f[b,y,x,a] = img[(y*20+x)*1568 + b*32 + a]
// out[r, p, q, a] : bin = p*7+q ; x-coords use p, y-coords use q (reference's bin_x/bin_y).
// Per bin: 2x2 sample points at bin corners, bilinear each, masked mean (/4).

#define NUM_ROIS 8192
#define NBIN 49
#define CH 1568          // 49*32
#define IMG_H 20
#define IMG_W 20

typedef float vf4 __attribute__((ext_vector_type(4)));

__global__ __launch_bounds__(256) void psroi_kernel(
    const float* __restrict__ img,
    const float* __restrict__ rois,
    float* __restrict__ out)
{
    const unsigned tid = blockIdx.x * 256u + threadIdx.x;
    const unsigned g   = tid >> 3;          // (roi, bin) pair index
    const unsigned a4  = (tid & 7u) << 2;   // alpha offset: 0,4,...,28
    const unsigned r   = g / 49u;
    const unsigned bin = g - r * 49u;
    const unsigned p   = bin / 7u;          // bin_x (drives x)
    const unsigned q   = bin - p * 7u;      // bin_y (drives y)

    const vf4 roi = ((const vf4*)rois)[r];
    const float x = roi.x, y = roi.y, w = roi.z, h = roi.w;
    const float step_x = w * (1.0f / 7.0f);
    const float step_y = h * (1.0f / 7.0f);
    const float s = 19.0f / 20.0f;

    float sx[2], sy[2];
    sx[0] = (x + (float)p * step_x) * s;
    sx[1] = (x + (float)(p + 1) * step_x) * s;
    sy[0] = (y + (float)q * step_y) * s;
    sy[1] = (y + (float)(q + 1) * step_y) * s;

    int x0i[2], x1i[2], y0i[2], y1i[2];
    float wx[2], wy[2];
    bool vx[2], vy[2];
#pragma unroll
    for (int i = 0; i < 2; ++i) {
        float c = sx[i];
        vx[i] = (c >= 0.0f) && (c <= 19.0f);
        float fc = floorf(c);
        wx[i] = c - fc;
        int c0 = (int)fc;
        c0 = max(0, min(c0, 19));
        x0i[i] = c0;
        x1i[i] = min(c0 + 1, 19);

        c = sy[i];
        vy[i] = (c >= 0.0f) && (c <= 19.0f);
        fc = floorf(c);
        wy[i] = c - fc;
        c0 = (int)fc;
        c0 = max(0, min(c0, 19));
        y0i[i] = c0;
        y1i[i] = min(c0 + 1, 19);
    }

    const float* base = img + bin * 32u + a4;
    float accx = 0.f, accy = 0.f, accz = 0.f, accw = 0.f;

#pragma unroll
    for (int iy = 0; iy < 2; ++iy) {
#pragma unroll
        for (int ix = 0; ix < 2; ++ix) {
            const int r0 = y0i[iy] * IMG_W;
            const int r1 = y1i[iy] * IMG_W;
            const vf4 v00 = *(const vf4*)(base + (size_t)(r0 + x0i[ix]) * CH);
            const vf4 v01 = *(const vf4*)(base + (size_t)(r0 + x1i[ix]) * CH);
            const vf4 v10 = *(const vf4*)(base + (size_t)(r1 + x0i[ix]) * CH);
            const vf4 v11 = *(const vf4*)(base + (size_t)(r1 + x1i[ix]) * CH);

            const float m   = (vy[iy] && vx[ix]) ? 0.25f : 0.0f;  // fold mean /4 into mask
            const float ay  = wy[iy], ax = wx[ix];
            const float w00 = (1.f - ay) * (1.f - ax) * m;
            const float w01 = (1.f - ay) * ax * m;
            const float w10 = ay * (1.f - ax) * m;
            const float w11 = ay * ax * m;

            accx += v00.x * w00 + v01.x * w01 + v10.x * w10 + v11.x * w11;
            accy += v00.y * w00 + v01.y * w01 + v10.y * w10 + v11.y * w11;
            accz += v00.z * w00 + v01.z * w01 + v10.z * w10 + v11.z * w11;
            accw += v00.w * w00 + v01.w * w01 + v10.w * w10 + v11.w * w11;
        }
    }

    vf4 res;
    res.x = accx; res.y = accy; res.z = accz; res.w = accw;
    __builtin_nontemporal_store(res, (vf4*)(out + (size_t)g * 32u + a4));
}

extern "C" void kernel_launch(void* const* d_in, const int* in_sizes, int n_in,
                              void* d_out, int out_size, void* d_ws, size_t ws_size,
                              hipStream_t stream) {
    const float* img  = (const float*)d_in[0];
    const float* rois = (const float*)d_in[1];
    float* out = (float*)d_out;
    // total threads = 8192 * 49 * 8 = 3,211,264 = 12,544 blocks * 256 (exact)
    hipLaunchKernelGGL(psroi_kernel, dim3(12544), dim3(256), 0, stream, img, rois, out);
}

// Round 3
// 85.503 us; speedup vs baseline: 1.0866x; 1.0866x over previous
//
#include <hip/hip_runtime.h>

// PS-ROI Align: img (1,20,20,1568) f32, rois (1,8192,4) f32 -> out (1,8192,7,7,32) f32
// f[b,y,x,a] = img[(y*20+x)*1568 + b*32 + a]
// out[r, p, q, a] : bin = p*7+q ; x-coords use p, y-coords use q.
// Key fact: bin span = (w/7)*0.95 <= 0.815 px, so the 2x2 sample points' bilinear
// corners collapse to a 3x3 cell grid. Bilinear+mask is separable, so we factorize
// into per-axis 3-entry weight vectors and do 9 loads instead of 16.

#define NBIN 49
#define CH 1568          // 49*32
#define IMG_W 20

typedef float vf4 __attribute__((ext_vector_type(4)));

// Distribute the two samples' 1D bilinear weights (with validity mask and
// reference clamping semantics) onto 3 consecutive cells starting at base b.
__device__ __forceinline__ void axis_weights(float s0, float s1,
                                             int& b, float& W0, float& W1, float& W2)
{
    const float f0 = floorf(s0), f1 = floorf(s1);
    const float w0 = s0 - f0,    w1 = s1 - f1;
    const float v0 = (s0 >= 0.f && s0 <= 19.f) ? 1.f : 0.f;
    const float v1 = (s1 >= 0.f && s1 <= 19.f) ? 1.f : 0.f;
    const int c00 = min(max((int)f0, 0), 19);
    const int c01 = min(c00 + 1, 19);
    const int c10 = min(max((int)f1, 0), 19);   // s1 > s0 => c10 in {c00, c00+1}
    const int c11 = min(c10 + 1, 19);
    b = c00;
    W0 = v0 * (1.f - w0);        // offset of c00 is 0 by construction
    W1 = 0.f; W2 = 0.f;
    float t = v0 * w0;           // goes to c01 - b in {0,1}
    if (c01 == b) W0 += t; else W1 += t;
    t = v1 * (1.f - w1);         // goes to c10 - b in {0,1}
    if (c10 == b) W0 += t; else W1 += t;
    t = v1 * w1;                 // goes to c11 - b in {0,1,2}
    const int d = c11 - b;
    W0 += (d == 0) ? t : 0.f;
    W1 += (d == 1) ? t : 0.f;
    W2 += (d == 2) ? t : 0.f;
}

__global__ __launch_bounds__(256) void psroi_kernel(
    const float* __restrict__ img,
    const float* __restrict__ rois,
    float* __restrict__ out)
{
    const unsigned tid = blockIdx.x * 256u + threadIdx.x;
    const unsigned g   = tid >> 3;          // (roi, bin) pair index
    const unsigned a4  = (tid & 7u) << 2;   // alpha offset: 0,4,...,28
    const unsigned r   = g / 49u;
    const unsigned bin = g - r * 49u;
    const unsigned p   = bin / 7u;          // bin_x (drives x)
    const unsigned q   = bin - p * 7u;      // bin_y (drives y)

    const vf4 roi = ((const vf4*)rois)[r];
    const float x = roi.x, y = roi.y, w = roi.z, h = roi.w;
    const float step_x = w * (1.0f / 7.0f);
    const float step_y = h * (1.0f / 7.0f);
    const float s = 19.0f / 20.0f;

    const float sx0 = (x + (float)p * step_x) * s;
    const float sx1 = (x + (float)(p + 1) * step_x) * s;
    const float sy0 = (y + (float)q * step_y) * s;
    const float sy1 = (y + (float)(q + 1) * step_y) * s;

    int bx, by;
    float WX0, WX1, WX2, WY0, WY1, WY2;
    axis_weights(sx0, sx1, bx, WX0, WX1, WX2);
    axis_weights(sy0, sy1, by, WY0, WY1, WY2);
    // fold the mean (/4) into the row weights
    WY0 *= 0.25f; WY1 *= 0.25f; WY2 *= 0.25f;

    const float WX[3] = { WX0, WX1, WX2 };
    const float WY[3] = { WY0, WY1, WY2 };
    const int col[3] = { bx, min(bx + 1, 19), min(bx + 2, 19) };
    const int row[3] = { by, min(by + 1, 19), min(by + 2, 19) };

    const float* base = img + bin * 32u + a4;
    vf4 acc = { 0.f, 0.f, 0.f, 0.f };

#pragma unroll
    for (int i = 0; i < 3; ++i) {
        const float* rp = base + (size_t)row[i] * (IMG_W * CH);
#pragma unroll
        for (int j = 0; j < 3; ++j) {
            const vf4 v = *(const vf4*)(rp + (size_t)col[j] * CH);
            const float wgt = WY[i] * WX[j];   // zero weight for unused cells
            acc += wgt * v;
        }
    }

    __builtin_nontemporal_store(acc, (vf4*)(out + (size_t)g * 32u + a4));
}

extern "C" void kernel_launch(void* const* d_in, const int* in_sizes, int n_in,
                              void* d_out, int out_size, void* d_ws, size_t ws_size,
                              hipStream_t stream) {
    const float* img  = (const float*)d_in[0];
    const float* rois = (const float*)d_in[1];
    float* out = (float*)d_out;
    // total threads = 8192 * 49 * 8 = 3,211,264 = 12,544 blocks * 256 (exact)
    hipLaunchKernelGGL(psroi_kernel, dim3(12544), dim3(256), 0, stream, img, rois, out);
}